// Round 6
// baseline (409.308 us; speedup 1.0000x reference)
//
#include <hip/hip_runtime.h>
#include <hip/hip_fp16.h>

// DynamicRouting (capsule routing), MI355X / gfx950.
// votes: [B=128, I=2048, O=32, P=4] fp32 (128 MiB). activations_in unused.
// b_ij^(t)[b,i,o] = sum_{tau<t} dot(votes[b,i,o,:], v^tau[b,o,:]) -> b_ij never materialized.
//
// R11 vs R10 (236 us) / R5 (230.4 us, best):
//  Measured: fp32 L3 re-read passes run ~27 us each (~5 TB/s) -> Infinity Cache gives
//  HBM-class BW for streaming; BYTES are the currency -> R5's fp16 copy structure wins.
//  R11 keeps R5's proven pass bodies and shaves the structural overhead:
//   - 4 kernels -> 3: finalize folded into t2 via single-shot atomic fan-in
//     (ONE ACQ_REL atomicAdd per block, NO spinning -- not the R6-R8 spin barrier).
//   - t1's last-arriving block per b publishes vsum = v^0+v^1, so t2 blocks load
//     16 B instead of re-reducing 16 KB of partials each.
//   - counter zeroing folded into t0 (no init kernel).
//  Numerics identical to R5 (t=0 sum fp32 from original votes; t1/t2 fp16 copy;
//  absmax 0.0039).

#define BATCH 128
#define IC 2048
#define OC 32
#define POSE 4
#define REPS 1e-7f
#define CHUNKS 16
#define CHUNK_I (IC / CHUNKS)          // 128 input capsules per block
#define BLOCK_T 256
#define GROUPS (BLOCK_T / 32)          // 8 o-groups per block
#define ILP 4
#define STEPS (CHUNK_I / (GROUPS * ILP))  // 4 steps, 4 i's per thread per step

// partials layout: [t][b][chunk][o] float4
#define PART_IDX(t, b, c, o) ((((size_t)(t) * BATCH + (b)) * CHUNKS + (c)) * OC + (o))

struct alignas(8) half4v { __half2 xy, zw; };

__device__ __forceinline__ half4v f2h(const float4 v) {
    half4v h;
    h.xy = __float22half2_rn(make_float2(v.x, v.y));
    h.zw = __float22half2_rn(make_float2(v.z, v.w));
    return h;
}
__device__ __forceinline__ float4 h2f(const half4v h) {
    const float2 a = __half22float2(h.xy);
    const float2 b = __half22float2(h.zw);
    return make_float4(a.x, a.y, b.x, b.y);
}

__device__ __forceinline__ float dot4(const float4 a, const float4 b) {
    return a.x*b.x + a.y*b.y + a.z*b.z + a.w*b.w;
}

// squash: v = (n2/(1+n2)) * s / sqrt(n2),  n2 = |s|^2 + eps
__device__ __forceinline__ float4 squash4(const float4 s) {
    const float n2 = s.x*s.x + s.y*s.y + s.z*s.z + s.w*s.w + REPS;
    const float f = n2 / (1.f + n2) * rsqrtf(n2);
    return make_float4(f*s.x, f*s.y, f*s.z, f*s.w);
}

// sum the 16 chunk partials for (b,o) of iteration t, apply scale, squash
__device__ __forceinline__ float4 reduce_squash(
    const float4* __restrict__ partials, int t, int b, int o, float scale)
{
    float4 acc = make_float4(0.f, 0.f, 0.f, 0.f);
    #pragma unroll
    for (int c = 0; c < CHUNKS; ++c) {
        const float4 p = partials[PART_IDX(t, b, c, o)];
        acc.x += p.x; acc.y += p.y; acc.z += p.z; acc.w += p.w;
    }
    acc.x *= scale; acc.y *= scale; acc.z *= scale; acc.w *= scale;
    return squash4(acc);
}

// block-reduce 8 group partials per o, write one chunk partial (no atomics)
__device__ __forceinline__ void block_reduce_store(
    float4 s_acc, float4* lds_s, float4* __restrict__ partials,
    int t, int b, int chunk, int g, int o)
{
    lds_s[g * 32 + o] = s_acc;
    __syncthreads();
    if (threadIdx.x < 32) {
        float4 tot = lds_s[o];
        #pragma unroll
        for (int gg = 1; gg < GROUPS; ++gg) {
            const float4 x = lds_s[gg * 32 + o];
            tot.x += x.x; tot.y += x.y; tot.z += x.z; tot.w += x.w;
        }
        partials[PART_IDX(t, b, chunk, o)] = tot;   // 512 B coalesced
    }
}

// single-shot fan-in: returns true in ALL threads of the LAST-arriving block of
// this b-group. One ACQ_REL atomicAdd per block -- no spinning, no polling.
// Release: __syncthreads drained this block's partial stores to L2 (vmcnt(0));
// __threadfence + ACQ_REL RMW write back L2 device-wide. Acquire: the RMW's
// acquire invalidates the last block's L2; the partial lines it then reads were
// never touched by it -> L1 cannot hold stale copies.
__device__ __forceinline__ bool fanin_last(unsigned int* cnt, int* last_s) {
    __syncthreads();
    if (threadIdx.x == 0) {
        __threadfence();
        const unsigned old = __hip_atomic_fetch_add(
            cnt, 1u, __ATOMIC_ACQ_REL, __HIP_MEMORY_SCOPE_AGENT);
        *last_s = (old == CHUNKS - 1);
    }
    __syncthreads();
    return *last_s != 0;
}

// softmax over o (32 lanes) + weighted accumulate for one chunk of fp16 votes.
// __shfl_xor masks 16..1 stay within each 32-lane half of the wave64 (one o-group).
__device__ __forceinline__ float4 pass_accum(
    const half4v* __restrict__ cb, int i0, int g, int o, const float4 vh)
{
    float4 s_acc = make_float4(0.f, 0.f, 0.f, 0.f);
    #pragma unroll
    for (int step = 0; step < STEPS; ++step) {
        const int ia = i0 + step * (GROUPS * ILP) + g;
        const float4 v0 = h2f(cb[(size_t)(ia + 0 * GROUPS) * OC + o]);  // 512 B/wave
        const float4 v1 = h2f(cb[(size_t)(ia + 1 * GROUPS) * OC + o]);
        const float4 v2 = h2f(cb[(size_t)(ia + 2 * GROUPS) * OC + o]);
        const float4 v3 = h2f(cb[(size_t)(ia + 3 * GROUPS) * OC + o]);

        const float l0 = dot4(v0, vh);
        const float l1 = dot4(v1, vh);
        const float l2 = dot4(v2, vh);
        const float l3 = dot4(v3, vh);
        // no max-subtraction: |logit| <~ 16 worst case (|vh01|<2) -> fp32 exp safe
        float e0 = __expf(l0), e1 = __expf(l1), e2 = __expf(l2), e3 = __expf(l3);
        float t0 = e0, t1 = e1, t2 = e2, t3 = e3;
        #pragma unroll
        for (int d = 16; d >= 1; d >>= 1) {
            t0 += __shfl_xor(t0, d);
            t1 += __shfl_xor(t1, d);
            t2 += __shfl_xor(t2, d);
            t3 += __shfl_xor(t3, d);
        }
        const float c0 = e0 * __builtin_amdgcn_rcpf(t0);
        const float c1 = e1 * __builtin_amdgcn_rcpf(t1);
        const float c2 = e2 * __builtin_amdgcn_rcpf(t2);
        const float c3 = e3 * __builtin_amdgcn_rcpf(t3);

        s_acc.x += c0*v0.x + c1*v1.x + c2*v2.x + c3*v3.x;
        s_acc.y += c0*v0.y + c1*v1.y + c2*v2.y + c3*v3.y;
        s_acc.z += c0*v0.z + c1*v1.z + c2*v2.z + c3*v3.z;
        s_acc.w += c0*v0.w + c1*v1.w + c2*v2.w + c3*v3.w;
    }
    return s_acc;
}

// ---- kernel 1: t=0 stream fp32 votes, mean-reduce, emit fp16 copy, zero counters ----
__global__ __launch_bounds__(BLOCK_T) void routing_t0(
    const float4* __restrict__ votes,
    half4v* __restrict__ v16,            // [B*IC*OC] fp16 copy (ws)
    float4* __restrict__ partials,
    unsigned int* __restrict__ counters)
{
    // counters used by t1 (lines 0..127) and t2 (lines 128..255); ws is poisoned
    // each iteration, so zero here (visible to t1/t2 via kernel boundary).
    if (blockIdx.x == 0) counters[threadIdx.x * 32] = 0;

    const int blk   = blockIdx.x;
    const int b     = blk >> 4;
    const int chunk = blk & (CHUNKS - 1);
    const int o     = threadIdx.x & 31;
    const int g     = threadIdx.x >> 5;

    __shared__ float4 lds_s[GROUPS * 32];

    float4 s_acc = make_float4(0.f, 0.f, 0.f, 0.f);
    const float4* vb = votes + (size_t)b * IC * OC;
    half4v* cb = v16 + (size_t)b * IC * OC;
    const int i0 = chunk * CHUNK_I;

    #pragma unroll
    for (int step = 0; step < STEPS; ++step) {
        const int ia = i0 + step * (GROUPS * ILP) + g;
        const size_t e0 = (size_t)(ia + 0 * GROUPS) * OC + o;
        const size_t e1 = (size_t)(ia + 1 * GROUPS) * OC + o;
        const size_t e2 = (size_t)(ia + 2 * GROUPS) * OC + o;
        const size_t e3 = (size_t)(ia + 3 * GROUPS) * OC + o;
        const float4 v0 = vb[e0];    // wave: 1 KiB contiguous each
        const float4 v1 = vb[e1];
        const float4 v2 = vb[e2];
        const float4 v3 = vb[e3];

        // softmax(0) == 1/32 uniform; 1/32 applied by downstream reducer
        s_acc.x += (v0.x + v1.x) + (v2.x + v3.x);
        s_acc.y += (v0.y + v1.y) + (v2.y + v3.y);
        s_acc.z += (v0.z + v1.z) + (v2.z + v3.z);
        s_acc.w += (v0.w + v1.w) + (v2.w + v3.w);

        cb[e0] = f2h(v0);            // wave: 512 B contiguous each
        cb[e1] = f2h(v1);
        cb[e2] = f2h(v2);
        cb[e3] = f2h(v3);
    }

    block_reduce_store(s_acc, lds_s, partials, 0, b, chunk, g, o);
}

// ---- kernel 2: t=1 pass; last block per b publishes vsum = v^0 + v^1 ----
__global__ __launch_bounds__(BLOCK_T) void routing_t1(
    const half4v* __restrict__ v16,
    float4* __restrict__ partials,
    float4* __restrict__ vsum,           // [B][O] float4
    unsigned int* __restrict__ counters)
{
    const int blk   = blockIdx.x;
    const int b     = blk >> 4;
    const int chunk = blk & (CHUNKS - 1);
    const int o     = threadIdx.x & 31;
    const int g     = threadIdx.x >> 5;

    __shared__ float4 lds_s[GROUPS * 32];
    __shared__ float4 vh_s[32];
    __shared__ int    last_s;

    if (threadIdx.x < 32)
        vh_s[o] = reduce_squash(partials, 0, b, o, 1.f / 32.f);  // v^0
    __syncthreads();
    const float4 vh0 = vh_s[o];

    const float4 s1 = pass_accum(v16 + (size_t)b * IC * OC, chunk * CHUNK_I, g, o, vh0);
    __syncthreads();   // protect lds_s reuse (vh_s/lds_s phases)
    block_reduce_store(s1, lds_s, partials, 1, b, chunk, g, o);

    if (fanin_last(&counters[b * 32], &last_s)) {
        if (threadIdx.x < 32) {
            const float4 v1 = reduce_squash(partials, 1, b, o, 1.f);   // v^1
            // t=2 logit = dot(v, v0) + dot(v, v1) == dot(v, v0+v1)
            vsum[b * OC + o] = make_float4(vh0.x + v1.x, vh0.y + v1.y,
                                           vh0.z + v1.z, vh0.w + v1.w);
        }
    }
}

// ---- kernel 3: t=2 pass; last block per b squashes + writes outputs ----
__global__ __launch_bounds__(BLOCK_T) void routing_t2(
    const half4v* __restrict__ v16,
    float4* __restrict__ partials,
    const float4* __restrict__ vsum,
    float* __restrict__ out,             // poses [B,O,P] then acts [B,O,1]
    unsigned int* __restrict__ counters)
{
    const int blk   = blockIdx.x;
    const int b     = blk >> 4;
    const int chunk = blk & (CHUNKS - 1);
    const int o     = threadIdx.x & 31;
    const int g     = threadIdx.x >> 5;

    __shared__ float4 lds_s[GROUPS * 32];
    __shared__ int    last_s;

    const float4 vh01 = vsum[b * OC + o];   // 16 B, L1/L2 broadcast

    const float4 s2 = pass_accum(v16 + (size_t)b * IC * OC, chunk * CHUNK_I, g, o, vh01);
    block_reduce_store(s2, lds_s, partials, 2, b, chunk, g, o);

    if (fanin_last(&counters[(BATCH + b) * 32], &last_s)) {
        if (threadIdx.x < 32) {
            const float4 v = reduce_squash(partials, 2, b, o, 1.f);
            ((float4*)out)[b * OC + o] = v;                            // poses_out
            const float a = sqrtf(v.x*v.x + v.y*v.y + v.z*v.z + v.w*v.w + REPS);
            out[BATCH * OC * POSE + b * OC + o] = a;                   // activations
        }
    }
}

extern "C" void kernel_launch(void* const* d_in, const int* in_sizes, int n_in,
                              void* d_out, int out_size, void* d_ws, size_t ws_size,
                              hipStream_t stream) {
    const float4* votes = (const float4*)d_in[0];
    // d_in[1] (activations_in) unused by the reference.

    // ws layout: counters (32 KiB: 256 x 128B lines) | partials (3 MiB) |
    //            vsum (64 KiB) | fp16 votes copy (64 MiB); headroom to 4 MiB pad.
    unsigned int* counters = (unsigned int*)d_ws;
    float4* partials = (float4*)((char*)d_ws + 32 * 1024);
    float4* vsum     = (float4*)((char*)d_ws + 32 * 1024 + (size_t)3 * 1024 * 1024);
    half4v* v16      = (half4v*)((char*)d_ws + (size_t)4 * 1024 * 1024);

    routing_t0<<<BATCH * CHUNKS, BLOCK_T, 0, stream>>>(votes, v16, partials, counters);
    routing_t1<<<BATCH * CHUNKS, BLOCK_T, 0, stream>>>(v16, partials, vsum, counters);
    routing_t2<<<BATCH * CHUNKS, BLOCK_T, 0, stream>>>(v16, partials, vsum,
                                                       (float*)d_out, counters);
}

// Round 7
// 245.644 us; speedup vs baseline: 1.6663x; 1.6663x over previous
//
#include <hip/hip_runtime.h>
#include <hip/hip_fp16.h>

// DynamicRouting (capsule routing), MI355X / gfx950.
// votes: [B=128, I=2048, O=32, P=4] fp32 (128 MiB). activations_in unused.
// b_ij^(t)[b,i,o] = sum_{tau<t} dot(votes[b,i,o,:], v^tau[b,o,:]) -> b_ij never materialized.
//
// R12 vs R11 (409 us) / R5 (230.4 us, session best):
//  R11 post-mortem: ONE __threadfence + ACQ_REL atomic per block (the "single-shot"
//  fan-in) = 110 us per pass -- gfx950 release fences emit L2 writeback/invalidate,
//  2048 of them serialize at the coherence point (matches R8's fence-storm scaling).
//  RULE: zero device-scope fences; kernel boundaries are the only cross-block sync.
//  R12 = R5's proven 4-kernel structure (230.4) + micro-optimizations:
//   - nt-loads for fp32 votes (dead after t0) and nt-stores for the fp16 copy:
//     targets t0's measured ~5 TB/s mixed-stream rate (pure fills hit 7 TB/s).
//   - fp16 copy in PRIVATE 32 B/thread slots: t0 writes 2x16 B per step (wave =
//     2 KiB contiguous), passes read 2x16 B -- half the memory instructions,
//     identical math and bytes.
//   - no counters / no fences / no vsum: pass<2> re-derives v0,v1 from partials
//     (proven R10); finalize stays a separate tiny kernel.
//  Numerics identical to R5 (absmax 0.00390625; t0 sums fp32, passes use fp16).

#define BATCH 128
#define IC 2048
#define OC 32
#define POSE 4
#define REPS 1e-7f
#define CHUNKS 16
#define CHUNK_I (IC / CHUNKS)             // 128 input capsules per block
#define BLOCK_T 256
#define GROUPS (BLOCK_T / 32)             // 8 o-groups per block
#define ILP 4
#define STEPS (CHUNK_I / (GROUPS * ILP))  // 4 steps, 4 i's per thread per step

// partials layout: [t][b][chunk][o] float4
#define PART_IDX(t, b, c, o) ((((size_t)(t) * BATCH + (b)) * CHUNKS + (c)) * OC + (o))

typedef float        f32x4 __attribute__((ext_vector_type(4)));
typedef unsigned int u32x4 __attribute__((ext_vector_type(4)));

__device__ __forceinline__ unsigned packh2(const float a, const float b) {
    union { __half2 h; unsigned u; } c;
    c.h = __float22half2_rn(make_float2(a, b));
    return c.u;
}
__device__ __forceinline__ float4 unpackh2(const unsigned lo, const unsigned hi) {
    union { unsigned u; __half2 h; } a, b;
    a.u = lo; b.u = hi;
    const float2 f0 = __half22float2(a.h);
    const float2 f1 = __half22float2(b.h);
    return make_float4(f0.x, f0.y, f1.x, f1.y);
}

__device__ __forceinline__ float dot4(const float4 a, const float4 b) {
    return a.x*b.x + a.y*b.y + a.z*b.z + a.w*b.w;
}

// squash: v = (n2/(1+n2)) * s / sqrt(n2),  n2 = |s|^2 + eps
__device__ __forceinline__ float4 squash4(const float4 s) {
    const float n2 = s.x*s.x + s.y*s.y + s.z*s.z + s.w*s.w + REPS;
    const float f = n2 / (1.f + n2) * rsqrtf(n2);
    return make_float4(f*s.x, f*s.y, f*s.z, f*s.w);
}

// sum the 16 chunk partials for (b,o) of iteration t, apply scale, squash
__device__ __forceinline__ float4 reduce_squash(
    const float4* __restrict__ partials, int t, int b, int o, float scale)
{
    float4 acc = make_float4(0.f, 0.f, 0.f, 0.f);
    #pragma unroll
    for (int c = 0; c < CHUNKS; ++c) {
        const float4 p = partials[PART_IDX(t, b, c, o)];
        acc.x += p.x; acc.y += p.y; acc.z += p.z; acc.w += p.w;
    }
    acc.x *= scale; acc.y *= scale; acc.z *= scale; acc.w *= scale;
    return squash4(acc);
}

// block-reduce 8 group partials per o, write one chunk partial (no atomics)
__device__ __forceinline__ void block_reduce_store(
    float4 s_acc, float4* lds_s, float4* __restrict__ partials,
    int t, int b, int chunk, int g, int o)
{
    lds_s[g * 32 + o] = s_acc;
    __syncthreads();
    if (threadIdx.x < 32) {
        float4 tot = lds_s[o];
        #pragma unroll
        for (int gg = 1; gg < GROUPS; ++gg) {
            const float4 x = lds_s[gg * 32 + o];
            tot.x += x.x; tot.y += x.y; tot.z += x.z; tot.w += x.w;
        }
        partials[PART_IDX(t, b, chunk, o)] = tot;   // 512 B coalesced
    }
}

// ---- t=0: nt-stream fp32 votes, mean-reduce, emit fp16 copy (nt, private slots) ----
__global__ __launch_bounds__(BLOCK_T) void routing_t0(
    const f32x4* __restrict__ votes,
    u32x4* __restrict__ v16,             // fp16 copy, [blk][step][tid] 32 B slots
    float4* __restrict__ partials)
{
    const int blk   = blockIdx.x;
    const int b     = blk >> 4;
    const int chunk = blk & (CHUNKS - 1);
    const int o     = threadIdx.x & 31;
    const int g     = threadIdx.x >> 5;

    __shared__ float4 lds_s[GROUPS * 32];

    float4 s_acc = make_float4(0.f, 0.f, 0.f, 0.f);
    const f32x4* vb = votes + (size_t)b * IC * OC;
    const int i0 = chunk * CHUNK_I;

    #pragma unroll
    for (int step = 0; step < STEPS; ++step) {
        const int ia = i0 + step * (GROUPS * ILP) + g;
        // nt loads: fp32 votes are dead after this kernel -- don't cache them
        const f32x4 n0 = __builtin_nontemporal_load(&vb[(size_t)(ia + 0 * GROUPS) * OC + o]);
        const f32x4 n1 = __builtin_nontemporal_load(&vb[(size_t)(ia + 1 * GROUPS) * OC + o]);
        const f32x4 n2 = __builtin_nontemporal_load(&vb[(size_t)(ia + 2 * GROUPS) * OC + o]);
        const f32x4 n3 = __builtin_nontemporal_load(&vb[(size_t)(ia + 3 * GROUPS) * OC + o]);

        // softmax(0) == 1/32 uniform; 1/32 applied by downstream reducer
        s_acc.x += (n0.x + n1.x) + (n2.x + n3.x);
        s_acc.y += (n0.y + n1.y) + (n2.y + n3.y);
        s_acc.z += (n0.z + n1.z) + (n2.z + n3.z);
        s_acc.w += (n0.w + n1.w) + (n2.w + n3.w);

        // pack 4 quads -> two 16 B nt-stores into this thread's private 32 B slot
        u32x4 lo, hi;
        lo.x = packh2(n0.x, n0.y); lo.y = packh2(n0.z, n0.w);
        lo.z = packh2(n1.x, n1.y); lo.w = packh2(n1.z, n1.w);
        hi.x = packh2(n2.x, n2.y); hi.y = packh2(n2.z, n2.w);
        hi.z = packh2(n3.x, n3.y); hi.w = packh2(n3.z, n3.w);
        const size_t slot = ((size_t)(blk * STEPS + step) * BLOCK_T + threadIdx.x) * 2;
        __builtin_nontemporal_store(lo, &v16[slot + 0]);   // wave: 2 KiB contiguous
        __builtin_nontemporal_store(hi, &v16[slot + 1]);
    }

    block_reduce_store(s_acc, lds_s, partials, 0, b, chunk, g, o);
}

// ---- t=1 / t=2: fp16 pass; v-history re-derived from 8 KB of partials ----
template <int T>
__global__ __launch_bounds__(BLOCK_T) void routing_pass(
    const u32x4* __restrict__ v16,
    float4* __restrict__ partials)
{
    const int blk   = blockIdx.x;
    const int b     = blk >> 4;
    const int chunk = blk & (CHUNKS - 1);
    const int o     = threadIdx.x & 31;
    const int g     = threadIdx.x >> 5;

    __shared__ float4 lds_s[GROUPS * 32];
    __shared__ float4 vh_s[32];

    if (threadIdx.x < 32) {
        float4 vh = reduce_squash(partials, 0, b, o, 1.f / 32.f);    // v^0
        if (T == 2) {
            const float4 v1 = reduce_squash(partials, 1, b, o, 1.f); // v^1
            // t=2 logit = dot(v, v0) + dot(v, v1) == dot(v, v0+v1)
            vh.x += v1.x; vh.y += v1.y; vh.z += v1.z; vh.w += v1.w;
        }
        vh_s[o] = vh;
    }
    __syncthreads();
    const float4 vh = vh_s[o];

    float4 s_acc = make_float4(0.f, 0.f, 0.f, 0.f);
    #pragma unroll
    for (int step = 0; step < STEPS; ++step) {
        const size_t slot = ((size_t)(blk * STEPS + step) * BLOCK_T + threadIdx.x) * 2;
        const u32x4 lo = v16[slot + 0];          // wave: 2 KiB contiguous
        const u32x4 hi = v16[slot + 1];
        const float4 v0 = unpackh2(lo.x, lo.y);
        const float4 v1 = unpackh2(lo.z, lo.w);
        const float4 v2 = unpackh2(hi.x, hi.y);
        const float4 v3 = unpackh2(hi.z, hi.w);

        const float l0 = dot4(v0, vh);
        const float l1 = dot4(v1, vh);
        const float l2 = dot4(v2, vh);
        const float l3 = dot4(v3, vh);
        // no max-subtraction: |logit| <~ 16 worst case (|vh01|<2) -> fp32 exp safe
        float e0 = __expf(l0), e1 = __expf(l1), e2 = __expf(l2), e3 = __expf(l3);
        float t0 = e0, t1 = e1, t2 = e2, t3 = e3;
        // butterfly sums over the 32-lane o-group (masks 16..1 stay in-half)
        #pragma unroll
        for (int d = 16; d >= 1; d >>= 1) {
            t0 += __shfl_xor(t0, d);
            t1 += __shfl_xor(t1, d);
            t2 += __shfl_xor(t2, d);
            t3 += __shfl_xor(t3, d);
        }
        const float c0 = e0 * __builtin_amdgcn_rcpf(t0);
        const float c1 = e1 * __builtin_amdgcn_rcpf(t1);
        const float c2 = e2 * __builtin_amdgcn_rcpf(t2);
        const float c3 = e3 * __builtin_amdgcn_rcpf(t3);

        s_acc.x += c0*v0.x + c1*v1.x + c2*v2.x + c3*v3.x;
        s_acc.y += c0*v0.y + c1*v1.y + c2*v2.y + c3*v3.y;
        s_acc.z += c0*v0.z + c1*v1.z + c2*v2.z + c3*v3.z;
        s_acc.w += c0*v0.w + c1*v1.w + c2*v2.w + c3*v3.w;
    }

    __syncthreads();   // protect lds_s reuse (vh_s phase done)
    block_reduce_store(s_acc, lds_s, partials, T, b, chunk, g, o);
}

// ---- finalize: reduce t=2 partials, squash, write poses + activations ----
__global__ __launch_bounds__(256) void routing_finalize(
    const float4* __restrict__ partials,
    float* __restrict__ out)             // poses [B,O,P] then acts [B,O,1]
{
    const int idx = blockIdx.x * blockDim.x + threadIdx.x;  // one (b,o) per thread
    if (idx >= BATCH * OC) return;
    const int b = idx >> 5, o = idx & 31;
    const float4 v = reduce_squash(partials, 2, b, o, 1.f);
    ((float4*)out)[idx] = v;                                       // poses_out
    const float a = sqrtf(v.x*v.x + v.y*v.y + v.z*v.z + v.w*v.w + REPS);
    out[BATCH * OC * POSE + idx] = a;                              // activations
}

extern "C" void kernel_launch(void* const* d_in, const int* in_sizes, int n_in,
                              void* d_out, int out_size, void* d_ws, size_t ws_size,
                              hipStream_t stream) {
    const f32x4* votes = (const f32x4*)d_in[0];
    // d_in[1] (activations_in) unused by the reference.

    // ws layout: partials [3][B][CHUNKS][O] float4 (3 MiB) | pad | fp16 copy (64 MiB)
    float4* partials = (float4*)d_ws;
    u32x4*  v16      = (u32x4*)((char*)d_ws + (size_t)4 * 1024 * 1024);

    routing_t0<<<BATCH * CHUNKS, BLOCK_T, 0, stream>>>(votes, v16, partials);
    routing_pass<1><<<BATCH * CHUNKS, BLOCK_T, 0, stream>>>(v16, partials);
    routing_pass<2><<<BATCH * CHUNKS, BLOCK_T, 0, stream>>>(v16, partials);
    routing_finalize<<<(BATCH * OC + 255) / 256, 256, 0, stream>>>(
        partials, (float*)d_out);
}

// Round 8
// 230.318 us; speedup vs baseline: 1.7771x; 1.0665x over previous
//
#include <hip/hip_runtime.h>
#include <hip/hip_fp16.h>

// DynamicRouting (capsule routing), MI355X / gfx950.
// votes: [B=128, I=2048, O=32, P=4] fp32 (128 MiB). activations_in unused.
// b_ij^(t)[b,i,o] = sum_{tau<t} dot(votes[b,i,o,:], v^tau[b,o,:]) -> b_ij never materialized.
//
// R13 = R5 restored (230.4 us, session best) + two zero-risk tweaks.
//  R12 post-mortem: nt-stores + 32B-stride private slots caused partial-line HBM
//  writes (each 16B store covers half of each 128B line; nt defeats L2 merge) ->
//  +15 us. Reverted entirely: R5's 8B/lane stores are per-instruction contiguous
//  (512 B/wave) and L2-merge perfectly.
//  Session rules (measured): zero device-scope fences/atomics (R8: spin barrier
//  ~500 us, R11: one fence+atomic per block ~100 us/pass); kernel boundaries are
//  the only cross-block sync. Mixed R+W streams run ~5.15 TB/s (fabric), pure
//  streams ~6.4-6.9 TB/s; L3 residency is throughput-neutral for streaming.
//  Tweaks vs R5:
//   1. passes: step-0 copy-loads issued BEFORE the vh phase (latency hides under
//      partial-reduce + barrier; +8 VGPR, still <=64).
//   2. passes: removed vestigial 3rd __syncthreads (lds_s/vh_s don't alias).
//  Numerics identical to R5: t0 sums fp32 from original votes; passes use fp16
//  copy (absmax 0.00390625, well under 2e-2).

#define BATCH 128
#define IC 2048
#define OC 32
#define POSE 4
#define REPS 1e-7f
#define CHUNKS 16
#define CHUNK_I (IC / CHUNKS)             // 128 input capsules per block
#define BLOCK_T 256
#define GROUPS (BLOCK_T / 32)             // 8 o-groups per block
#define ILP 4
#define STEPS (CHUNK_I / (GROUPS * ILP))  // 4 steps, 4 i's per thread per step

// partials layout: [t][b][chunk][o] float4
#define PART_IDX(t, b, c, o) ((((size_t)(t) * BATCH + (b)) * CHUNKS + (c)) * OC + (o))

struct alignas(8) half4v { __half2 xy, zw; };

__device__ __forceinline__ half4v f2h(const float4 v) {
    half4v h;
    h.xy = __float22half2_rn(make_float2(v.x, v.y));
    h.zw = __float22half2_rn(make_float2(v.z, v.w));
    return h;
}
__device__ __forceinline__ float4 h2f(const half4v h) {
    const float2 a = __half22float2(h.xy);
    const float2 b = __half22float2(h.zw);
    return make_float4(a.x, a.y, b.x, b.y);
}

__device__ __forceinline__ float dot4(const float4 a, const float4 b) {
    return a.x*b.x + a.y*b.y + a.z*b.z + a.w*b.w;
}

// squash: v = (n2/(1+n2)) * s / sqrt(n2),  n2 = |s|^2 + eps
__device__ __forceinline__ float4 squash4(const float4 s) {
    const float n2 = s.x*s.x + s.y*s.y + s.z*s.z + s.w*s.w + REPS;
    const float f = n2 / (1.f + n2) * rsqrtf(n2);
    return make_float4(f*s.x, f*s.y, f*s.z, f*s.w);
}

// sum the 16 chunk partials for (b,o) of iteration t, apply scale, squash
__device__ __forceinline__ float4 reduce_squash(
    const float4* __restrict__ partials, int t, int b, int o, float scale)
{
    float4 acc = make_float4(0.f, 0.f, 0.f, 0.f);
    #pragma unroll
    for (int c = 0; c < CHUNKS; ++c) {
        const float4 p = partials[PART_IDX(t, b, c, o)];
        acc.x += p.x; acc.y += p.y; acc.z += p.z; acc.w += p.w;
    }
    acc.x *= scale; acc.y *= scale; acc.z *= scale; acc.w *= scale;
    return squash4(acc);
}

// block-reduce 8 group partials per o, write one chunk partial (no atomics)
__device__ __forceinline__ void block_reduce_store(
    float4 s_acc, float4* lds_s, float4* __restrict__ partials,
    int t, int b, int chunk, int g, int o)
{
    lds_s[g * 32 + o] = s_acc;
    __syncthreads();
    if (threadIdx.x < 32) {
        float4 tot = lds_s[o];
        #pragma unroll
        for (int gg = 1; gg < GROUPS; ++gg) {
            const float4 x = lds_s[gg * 32 + o];
            tot.x += x.x; tot.y += x.y; tot.z += x.z; tot.w += x.w;
        }
        partials[PART_IDX(t, b, chunk, o)] = tot;   // 512 B coalesced
    }
}

// softmax over o (32 lanes) + weighted accumulate for 4 fp16 quads.
// __shfl_xor masks 16..1 stay within each 32-lane half of the wave64 (one o-group).
__device__ __forceinline__ void accum4(const half4v q0, const half4v q1,
                                       const half4v q2, const half4v q3,
                                       const float4 vh, float4& s_acc)
{
    const float4 v0 = h2f(q0);
    const float4 v1 = h2f(q1);
    const float4 v2 = h2f(q2);
    const float4 v3 = h2f(q3);

    const float l0 = dot4(v0, vh);
    const float l1 = dot4(v1, vh);
    const float l2 = dot4(v2, vh);
    const float l3 = dot4(v3, vh);
    // no max-subtraction: |logit| <~ 16 worst case (|vh01|<2) -> fp32 exp safe
    float e0 = __expf(l0), e1 = __expf(l1), e2 = __expf(l2), e3 = __expf(l3);
    float t0 = e0, t1 = e1, t2 = e2, t3 = e3;
    #pragma unroll
    for (int d = 16; d >= 1; d >>= 1) {
        t0 += __shfl_xor(t0, d);
        t1 += __shfl_xor(t1, d);
        t2 += __shfl_xor(t2, d);
        t3 += __shfl_xor(t3, d);
    }
    const float c0 = e0 * __builtin_amdgcn_rcpf(t0);
    const float c1 = e1 * __builtin_amdgcn_rcpf(t1);
    const float c2 = e2 * __builtin_amdgcn_rcpf(t2);
    const float c3 = e3 * __builtin_amdgcn_rcpf(t3);

    s_acc.x += c0*v0.x + c1*v1.x + c2*v2.x + c3*v3.x;
    s_acc.y += c0*v0.y + c1*v1.y + c2*v2.y + c3*v3.y;
    s_acc.z += c0*v0.z + c1*v1.z + c2*v2.z + c3*v3.z;
    s_acc.w += c0*v0.w + c1*v1.w + c2*v2.w + c3*v3.w;
}

// ---- pass 0: stream fp32 votes, mean-reduce, emit fp16 copy ----
__global__ __launch_bounds__(BLOCK_T) void routing_pass0(
    const float4* __restrict__ votes,    // [B*IC*OC] float4
    half4v* __restrict__ v16,            // [B*IC*OC] fp16 copy (ws)
    float4* __restrict__ partials)
{
    const int blk   = blockIdx.x;
    const int b     = blk >> 4;
    const int chunk = blk & (CHUNKS - 1);
    const int o     = threadIdx.x & 31;
    const int g     = threadIdx.x >> 5;

    __shared__ float4 lds_s[GROUPS * 32];

    float4 s_acc = make_float4(0.f, 0.f, 0.f, 0.f);
    const float4* vb = votes + (size_t)b * IC * OC;
    half4v* cb = v16 + (size_t)b * IC * OC;
    const int i0 = chunk * CHUNK_I;

    #pragma unroll
    for (int step = 0; step < STEPS; ++step) {
        const int ia = i0 + step * (GROUPS * ILP) + g;
        const size_t e0 = (size_t)(ia + 0 * GROUPS) * OC + o;
        const size_t e1 = (size_t)(ia + 1 * GROUPS) * OC + o;
        const size_t e2 = (size_t)(ia + 2 * GROUPS) * OC + o;
        const size_t e3 = (size_t)(ia + 3 * GROUPS) * OC + o;
        const float4 v0 = vb[e0];    // wave: 1 KiB contiguous each
        const float4 v1 = vb[e1];
        const float4 v2 = vb[e2];
        const float4 v3 = vb[e3];

        // softmax(0) == 1/32 uniform; 1/32 applied by downstream reducer
        s_acc.x += (v0.x + v1.x) + (v2.x + v3.x);
        s_acc.y += (v0.y + v1.y) + (v2.y + v3.y);
        s_acc.z += (v0.z + v1.z) + (v2.z + v3.z);
        s_acc.w += (v0.w + v1.w) + (v2.w + v3.w);

        cb[e0] = f2h(v0);            // wave: 512 B contiguous each (L2-merged)
        cb[e1] = f2h(v1);
        cb[e2] = f2h(v2);
        cb[e3] = f2h(v3);
    }

    block_reduce_store(s_acc, lds_s, partials, 0, b, chunk, g, o);
}

// ---- passes 1-2: read fp16 copy; v-history derived from 8 KB of partials ----
template <int T>
__global__ __launch_bounds__(BLOCK_T) void routing_accum(
    const half4v* __restrict__ v16,      // fp16 votes copy
    float4* __restrict__ partials)
{
    const int blk   = blockIdx.x;
    const int b     = blk >> 4;
    const int chunk = blk & (CHUNKS - 1);
    const int o     = threadIdx.x & 31;
    const int g     = threadIdx.x >> 5;

    __shared__ float4 lds_s[GROUPS * 32];
    __shared__ float4 vh_s[32];

    const half4v* cb = v16 + (size_t)b * IC * OC;
    const int i0 = chunk * CHUNK_I;

    // tweak 1: issue step-0 copy-loads immediately (independent of vh);
    // their latency hides under the partial-reduce + barrier below.
    const int ia0 = i0 + g;
    const half4v p0 = cb[(size_t)(ia0 + 0 * GROUPS) * OC + o];
    const half4v p1 = cb[(size_t)(ia0 + 1 * GROUPS) * OC + o];
    const half4v p2 = cb[(size_t)(ia0 + 2 * GROUPS) * OC + o];
    const half4v p3 = cb[(size_t)(ia0 + 3 * GROUPS) * OC + o];

    if (threadIdx.x < 32) {
        float4 vh = reduce_squash(partials, 0, b, o, 1.f / 32.f);    // v^0
        if (T == 2) {
            const float4 v1 = reduce_squash(partials, 1, b, o, 1.f); // v^1
            // t=2 logit = dot(v, v0) + dot(v, v1) == dot(v, v0+v1)
            vh.x += v1.x; vh.y += v1.y; vh.z += v1.z; vh.w += v1.w;
        }
        vh_s[o] = vh;
    }
    __syncthreads();
    const float4 vh = vh_s[o];

    float4 s_acc = make_float4(0.f, 0.f, 0.f, 0.f);
    accum4(p0, p1, p2, p3, vh, s_acc);          // peeled step 0
    #pragma unroll
    for (int step = 1; step < STEPS; ++step) {
        const int ia = i0 + step * (GROUPS * ILP) + g;
        const half4v q0 = cb[(size_t)(ia + 0 * GROUPS) * OC + o];  // 512 B/wave
        const half4v q1 = cb[(size_t)(ia + 1 * GROUPS) * OC + o];
        const half4v q2 = cb[(size_t)(ia + 2 * GROUPS) * OC + o];
        const half4v q3 = cb[(size_t)(ia + 3 * GROUPS) * OC + o];
        accum4(q0, q1, q2, q3, vh, s_acc);
    }

    // tweak 2: no extra barrier here -- lds_s and vh_s don't alias, and
    // block_reduce_store barriers internally before any cross-group read.
    block_reduce_store(s_acc, lds_s, partials, T, b, chunk, g, o);
}

__global__ void routing_finalize(
    const float4* __restrict__ partials,
    float* __restrict__ out)             // d_out: poses [B,O,P] then acts [B,O,1]
{
    const int idx = blockIdx.x * blockDim.x + threadIdx.x;  // one (b,o) per thread
    if (idx >= BATCH * OC) return;
    const int b = idx >> 5, o = idx & 31;
    const float4 v = reduce_squash(partials, 2, b, o, 1.f);
    ((float4*)out)[idx] = v;                                       // poses_out
    const float a = sqrtf(v.x*v.x + v.y*v.y + v.z*v.z + v.w*v.w + REPS);
    out[BATCH * OC * POSE + idx] = a;                              // activations_out
}

extern "C" void kernel_launch(void* const* d_in, const int* in_sizes, int n_in,
                              void* d_out, int out_size, void* d_ws, size_t ws_size,
                              hipStream_t stream) {
    const float4* votes = (const float4*)d_in[0];
    // d_in[1] (activations_in) unused by the reference.

    // ws layout: partials [3][B][CHUNKS][O] float4 (3 MiB) | fp16 votes copy (64 MiB)
    float4* partials = (float4*)d_ws;
    half4v* v16 = (half4v*)((char*)d_ws + (size_t)3 * BATCH * CHUNKS * OC * sizeof(float4));

    routing_pass0<<<BATCH * CHUNKS, BLOCK_T, 0, stream>>>(votes, v16, partials);
    routing_accum<1><<<BATCH * CHUNKS, BLOCK_T, 0, stream>>>(v16, partials);
    routing_accum<2><<<BATCH * CHUNKS, BLOCK_T, 0, stream>>>(v16, partials);
    routing_finalize<<<(BATCH * OC + 255) / 256, 256, 0, stream>>>(
        partials, (float*)d_out);
}